// Round 5
// baseline (118.159 us; speedup 1.0000x reference)
//
#include <hip/hip_runtime.h>

#define R_ 4
#define S_ 8
#define N_ 4096
#define D_ 64
#define W_ 8            // waves per block (K-split ways)
#define KC_ (N_ / W_)   // 512 K per wave
#define NCH_ (KC_ / 32) // 16 k-chunks per wave

typedef __attribute__((ext_vector_type(8))) short bf16x8;
typedef __attribute__((ext_vector_type(4))) float f32x4;

__device__ __forceinline__ unsigned short f2bf(float f) {
    unsigned int u = __float_as_uint(f);
    u = (u + 0x7FFFu + ((u >> 16) & 1u)) >> 16;   // RNE to bf16
    return (unsigned short)u;
}

// Kernel 1: ycombT[r][o][k] = bf16( coef[r] * sum_d x[r][k][d] * fc_w[r][o][d] )
__global__ __launch_bounds__(256) void prep_kernel(
    const float* __restrict__ theta, const float* __restrict__ tt,
    const float* __restrict__ x, const float* __restrict__ fc_w,
    unsigned short* __restrict__ ycombT) {
    int r  = blockIdx.x >> 6;
    int kb = blockIdx.x & 63;
    int tid = threadIdx.x;

    __shared__ float xs[64][64];
    __shared__ float ws[64][65];

    const float* xp = x    + ((size_t)r * N_ + (size_t)kb * 64) * D_;
    const float* wp = fc_w + (size_t)r * D_ * D_;
    for (int i = 0; i < 16; ++i) {
        int flat = i * 256 + tid;
        xs[flat >> 6][flat & 63] = xp[flat];
        ws[flat >> 6][flat & 63] = wp[flat];
    }
    float coef = 0.f;
#pragma unroll
    for (int s = 0; s < S_; ++s) coef += theta[r * S_ + s] * tt[r * S_ + s];
    __syncthreads();

    int o = tid & 63, kg = tid >> 6;
    for (int kl = kg; kl < 64; kl += 4) {
        float dot = 0.f;
#pragma unroll
        for (int d = 0; d < D_; ++d) dot += xs[kl][d] * ws[o][d];
        ycombT[(size_t)(r * D_ + o) * N_ + (size_t)kb * 64 + kl] = f2bf(coef * dot);
    }
}

// Kernel 2: one block per (relation, 16-row slab). 8 waves split K (8 x 512).
// k-chunk order circularly rotated per (block, wave) to spread concurrent
// accesses across DRAM channels (anti-camping). LDS-reduce, bias+PReLU.
__global__ __launch_bounds__(512) void gemm_kernel(
    const float* __restrict__ a, const unsigned short* __restrict__ ycombT,
    const float* __restrict__ fc_b, const float* __restrict__ alpha0p,
    float* __restrict__ out) {
    int bid = blockIdx.x;             // 1024 blocks
    int r   = bid & 3;
    int rb  = bid >> 2;
    int w    = threadIdx.x >> 6;      // wave = K-chunk index (0..7)
    int lane = threadIdx.x & 63;
    int l15  = lane & 15;
    int kg   = lane >> 4;

    const float* arow = a + ((size_t)(r * N_ + rb * 16 + l15)) * N_ + w * KC_ + kg * 8;
    const unsigned short* yb = ycombT + (size_t)r * D_ * N_ + w * KC_ + kg * 8;
    const unsigned short* b0 = yb + (size_t)(0 * 16 + l15) * N_;
    const unsigned short* b1 = yb + (size_t)(1 * 16 + l15) * N_;
    const unsigned short* b2 = yb + (size_t)(2 * 16 + l15) * N_;
    const unsigned short* b3 = yb + (size_t)(3 * 16 + l15) * N_;

    f32x4 acc0 = {0.f, 0.f, 0.f, 0.f};
    f32x4 acc1 = {0.f, 0.f, 0.f, 0.f};
    f32x4 acc2 = {0.f, 0.f, 0.f, 0.f};
    f32x4 acc3 = {0.f, 0.f, 0.f, 0.f};

    // Anti-camping rotation: start phase differs per (block, wave).
    int j0 = (bid * 7 + w * 3) & (NCH_ - 1);

#pragma unroll 4
    for (int j = 0; j < NCH_; ++j) {
        int k0 = ((j + j0) & (NCH_ - 1)) * 32;
        float4 af0 = *(const float4*)(arow + k0);
        float4 af1 = *(const float4*)(arow + k0 + 4);
        bf16x8 afr;
        afr[0] = (short)f2bf(af0.x); afr[1] = (short)f2bf(af0.y);
        afr[2] = (short)f2bf(af0.z); afr[3] = (short)f2bf(af0.w);
        afr[4] = (short)f2bf(af1.x); afr[5] = (short)f2bf(af1.y);
        afr[6] = (short)f2bf(af1.z); afr[7] = (short)f2bf(af1.w);
        bf16x8 bv0 = *(const bf16x8*)(b0 + k0);
        bf16x8 bv1 = *(const bf16x8*)(b1 + k0);
        bf16x8 bv2 = *(const bf16x8*)(b2 + k0);
        bf16x8 bv3 = *(const bf16x8*)(b3 + k0);
        acc0 = __builtin_amdgcn_mfma_f32_16x16x32_bf16(afr, bv0, acc0, 0, 0, 0);
        acc1 = __builtin_amdgcn_mfma_f32_16x16x32_bf16(afr, bv1, acc1, 0, 0, 0);
        acc2 = __builtin_amdgcn_mfma_f32_16x16x32_bf16(afr, bv2, acc2, 0, 0, 0);
        acc3 = __builtin_amdgcn_mfma_f32_16x16x32_bf16(afr, bv3, acc3, 0, 0, 0);
    }

    // Cross-wave K-reduction in LDS. C/D layout: col=c*16+l15, row=kg*4+j (m89).
    __shared__ float red[W_][16][65];
#pragma unroll
    for (int c = 0; c < 4; ++c) {
        f32x4 acc = (c == 0) ? acc0 : (c == 1) ? acc1 : (c == 2) ? acc2 : acc3;
#pragma unroll
        for (int j = 0; j < 4; ++j)
            red[w][kg * 4 + j][c * 16 + l15] = acc[j];
    }
    __syncthreads();

    const float alpha0 = *alpha0p;
    const float* fcb = fc_b + r * D_;
    const size_t diff_off = (size_t)R_ * N_ * D_;     // out = [latent | diffusions]
    int t = threadIdx.x;                              // 512 threads: 16 rows x 32 col-pairs
    int row = t >> 5, col0 = (t & 31) * 2;
    float2 v;
#pragma unroll
    for (int cc = 0; cc < 2; ++cc) {
        float s = fcb[col0 + cc];
#pragma unroll
        for (int ww = 0; ww < W_; ++ww) s += red[ww][row][col0 + cc];
        ((float*)&v)[cc] = (s >= 0.f) ? s : alpha0 * s;
    }
    *(float2*)(out + diff_off + ((size_t)(r * N_ + rb * 16 + row)) * D_ + col0) = v;
}

// Kernel 3: 1x1 conv over relation channels + PReLU.
__global__ __launch_bounds__(256) void conv_kernel(
    const float* __restrict__ conv_w, const float* __restrict__ conv_b,
    const float* __restrict__ alpha1p, float* __restrict__ out) {
    const size_t nd = (size_t)N_ * D_;
    const size_t diff_off = (size_t)R_ * nd;
    size_t i = ((size_t)blockIdx.x * 256 + threadIdx.x) * 4;   // float4 granularity

    float4 d0 = *(const float4*)(out + diff_off + 0 * nd + i);
    float4 d1 = *(const float4*)(out + diff_off + 1 * nd + i);
    float4 d2 = *(const float4*)(out + diff_off + 2 * nd + i);
    float4 d3 = *(const float4*)(out + diff_off + 3 * nd + i);
    const float alpha1 = *alpha1p;
#pragma unroll
    for (int s = 0; s < R_; ++s) {
        float w0 = conv_w[s * R_ + 0], w1 = conv_w[s * R_ + 1];
        float w2 = conv_w[s * R_ + 2], w3 = conv_w[s * R_ + 3];
        float cb = conv_b[s];
        float4 v;
        v.x = cb + w0 * d0.x + w1 * d1.x + w2 * d2.x + w3 * d3.x;
        v.y = cb + w0 * d0.y + w1 * d1.y + w2 * d2.y + w3 * d3.y;
        v.z = cb + w0 * d0.z + w1 * d1.z + w2 * d2.z + w3 * d3.z;
        v.w = cb + w0 * d0.w + w1 * d1.w + w2 * d2.w + w3 * d3.w;
        v.x = (v.x >= 0.f) ? v.x : alpha1 * v.x;
        v.y = (v.y >= 0.f) ? v.y : alpha1 * v.y;
        v.z = (v.z >= 0.f) ? v.z : alpha1 * v.z;
        v.w = (v.w >= 0.f) ? v.w : alpha1 * v.w;
        *(float4*)(out + s * nd + i) = v;
    }
}

extern "C" void kernel_launch(void* const* d_in, const int* in_sizes, int n_in,
                              void* d_out, int out_size, void* d_ws, size_t ws_size,
                              hipStream_t stream) {
    const float* theta  = (const float*)d_in[0];
    const float* tt     = (const float*)d_in[1];
    const float* a      = (const float*)d_in[2];
    const float* x      = (const float*)d_in[3];
    const float* fc_w   = (const float*)d_in[4];
    const float* fc_b   = (const float*)d_in[5];
    const float* conv_w = (const float*)d_in[6];
    const float* conv_b = (const float*)d_in[7];
    const float* alpha0 = (const float*)d_in[8];
    const float* alpha1 = (const float*)d_in[9];
    float* out = (float*)d_out;
    unsigned short* ycombT = (unsigned short*)d_ws;   // 2 MiB bf16

    prep_kernel<<<dim3(R_ * (N_ / 64)), dim3(256), 0, stream>>>(theta, tt, x, fc_w, ycombT);
    gemm_kernel<<<dim3((N_ / 16) * R_), dim3(512), 0, stream>>>(a, ycombT, fc_b, alpha0, out);
    conv_kernel<<<dim3((N_ * D_) / 4 / 256), dim3(256), 0, stream>>>(conv_w, conv_b, alpha1, out);
}

// Round 6
// 70.594 us; speedup vs baseline: 1.6738x; 1.6738x over previous
//
#include <hip/hip_runtime.h>

#define R_ 4
#define S_ 8
#define N_ 4096
#define D_ 64
#define KS_ 128          // K per stage
#define NST_ (N_ / KS_)  // 32 stages

typedef __attribute__((ext_vector_type(8))) short bf16x8;
typedef __attribute__((ext_vector_type(4))) float f32x4;

__device__ __forceinline__ unsigned short f2bf(float f) {
    unsigned int u = __float_as_uint(f);
    u = (u + 0x7FFFu + ((u >> 16) & 1u)) >> 16;   // RNE to bf16
    return (unsigned short)u;
}

__device__ __forceinline__ bf16x8 packbf(float4 u, float4 v) {
    bf16x8 f;
    f[0] = (short)f2bf(u.x); f[1] = (short)f2bf(u.y);
    f[2] = (short)f2bf(u.z); f[3] = (short)f2bf(u.w);
    f[4] = (short)f2bf(v.x); f[5] = (short)f2bf(v.y);
    f[6] = (short)f2bf(v.z); f[7] = (short)f2bf(v.w);
    return f;
}

// Kernel 1: ycombT[r][o][k] = bf16( coef[r] * sum_d x[r][k][d] * fc_w[r][o][d] )
__global__ __launch_bounds__(256) void prep_kernel(
    const float* __restrict__ theta, const float* __restrict__ tt,
    const float* __restrict__ x, const float* __restrict__ fc_w,
    unsigned short* __restrict__ ycombT) {
    int r  = blockIdx.x >> 6;
    int kb = blockIdx.x & 63;
    int tid = threadIdx.x;

    __shared__ float xs[64][64];
    __shared__ float ws[64][65];

    const float* xp = x    + ((size_t)r * N_ + (size_t)kb * 64) * D_;
    const float* wp = fc_w + (size_t)r * D_ * D_;
    for (int i = 0; i < 16; ++i) {
        int flat = i * 256 + tid;
        xs[flat >> 6][flat & 63] = xp[flat];
        ws[flat >> 6][flat & 63] = wp[flat];
    }
    float coef = 0.f;
#pragma unroll
    for (int s = 0; s < S_; ++s) coef += theta[r * S_ + s] * tt[r * S_ + s];
    __syncthreads();

    int o = tid & 63, kg = tid >> 6;
    for (int kl = kg; kl < 64; kl += 4) {
        float dot = 0.f;
#pragma unroll
        for (int d = 0; d < D_; ++d) dot += xs[kl][d] * ws[o][d];
        ycombT[(size_t)(r * D_ + o) * N_ + (size_t)kb * 64 + kl] = f2bf(coef * dot);
    }
}

// Kernel 2: block = (r, 64-row tile), full K. 8 waves: wm (16-row group) x wk
// (64-k half of each 128-k stage). B staged in LDS once per block (shared by
// all waves, 4x traffic cut), XOR-swizzled. A: register float4 + cvt, 1-stage
// prefetch. Cross-wk LDS reduction, bias+PReLU epilogue.
__global__ __launch_bounds__(512) void gemm_kernel(
    const float* __restrict__ a, const unsigned short* __restrict__ ycombT,
    const float* __restrict__ fc_b, const float* __restrict__ alpha0p,
    float* __restrict__ out) {
    int bid = blockIdx.x;             // 256 blocks
    int r   = bid & 3;
    int rb  = bid >> 2;               // 64-row tile index
    int tid  = threadIdx.x;
    int wave = tid >> 6;
    int wm   = wave & 3;              // 16-row group
    int wk   = wave >> 2;             // 64-k half per stage
    int lane = tid & 63;
    int l15  = lane & 15;
    int kg   = lane >> 4;

    __shared__ __align__(16) unsigned short bs[2][64][KS_];  // 2 x 16 KB
    __shared__ float red[4][16][65];

    // B staging mapping: thread -> row = tid>>3 (0..63), granules g2, g2+1 (16B units)
    int srow = tid >> 3, g2 = (tid & 7) * 2;
    int swz  = (srow & 7) << 1;                    // write-side XOR
    const unsigned short* ysrc = ycombT + (size_t)(r * D_ + srow) * N_ + g2 * 8;

    const float* arow = a + ((size_t)(r * N_ + rb * 64 + wm * 16 + l15)) * N_
                          + wk * 64 + kg * 8;

    f32x4 acc0 = {0.f, 0.f, 0.f, 0.f};
    f32x4 acc1 = {0.f, 0.f, 0.f, 0.f};
    f32x4 acc2 = {0.f, 0.f, 0.f, 0.f};
    f32x4 acc3 = {0.f, 0.f, 0.f, 0.f};

    // read-side swizzled slots (ushort offsets), per j (k-step within wk-half)
    int swzr = (l15 & 7) << 1;
    int sl0 = ((wk * 8 + 0 + kg) ^ swzr) * 8;
    int sl1 = ((wk * 8 + 4 + kg) ^ swzr) * 8;

    // prologue: stage 0
    float4 ac0 = *(const float4*)(arow + 0);
    float4 ac1 = *(const float4*)(arow + 4);
    float4 ac2 = *(const float4*)(arow + 32);
    float4 ac3 = *(const float4*)(arow + 36);
    uint4 bv0 = *(const uint4*)(ysrc);
    uint4 bv1 = *(const uint4*)(ysrc + 8);
    *(uint4*)&bs[0][srow][((g2    ) ^ swz) * 8] = bv0;
    *(uint4*)&bs[0][srow][((g2 + 1) ^ swz) * 8] = bv1;
    __syncthreads();
    bv0 = *(const uint4*)(ysrc + KS_);
    bv1 = *(const uint4*)(ysrc + KS_ + 8);
    float4 an0 = *(const float4*)(arow + KS_ + 0);
    float4 an1 = *(const float4*)(arow + KS_ + 4);
    float4 an2 = *(const float4*)(arow + KS_ + 32);
    float4 an3 = *(const float4*)(arow + KS_ + 36);

    for (int s = 0; s < NST_; ++s) {
        int buf = s & 1;
        bf16x8 af0 = packbf(ac0, ac1);
        bf16x8 af1 = packbf(ac2, ac3);
        bf16x8 b00 = *(const bf16x8*)&bs[buf][ 0 + l15][sl0];
        bf16x8 b10 = *(const bf16x8*)&bs[buf][16 + l15][sl0];
        bf16x8 b20 = *(const bf16x8*)&bs[buf][32 + l15][sl0];
        bf16x8 b30 = *(const bf16x8*)&bs[buf][48 + l15][sl0];
        acc0 = __builtin_amdgcn_mfma_f32_16x16x32_bf16(af0, b00, acc0, 0, 0, 0);
        acc1 = __builtin_amdgcn_mfma_f32_16x16x32_bf16(af0, b10, acc1, 0, 0, 0);
        acc2 = __builtin_amdgcn_mfma_f32_16x16x32_bf16(af0, b20, acc2, 0, 0, 0);
        acc3 = __builtin_amdgcn_mfma_f32_16x16x32_bf16(af0, b30, acc3, 0, 0, 0);
        bf16x8 b01 = *(const bf16x8*)&bs[buf][ 0 + l15][sl1];
        bf16x8 b11 = *(const bf16x8*)&bs[buf][16 + l15][sl1];
        bf16x8 b21 = *(const bf16x8*)&bs[buf][32 + l15][sl1];
        bf16x8 b31 = *(const bf16x8*)&bs[buf][48 + l15][sl1];
        acc0 = __builtin_amdgcn_mfma_f32_16x16x32_bf16(af1, b01, acc0, 0, 0, 0);
        acc1 = __builtin_amdgcn_mfma_f32_16x16x32_bf16(af1, b11, acc1, 0, 0, 0);
        acc2 = __builtin_amdgcn_mfma_f32_16x16x32_bf16(af1, b21, acc2, 0, 0, 0);
        acc3 = __builtin_amdgcn_mfma_f32_16x16x32_bf16(af1, b31, acc3, 0, 0, 0);

        ac0 = an0; ac1 = an1; ac2 = an2; ac3 = an3;
        if (s + 2 < NST_) {
            an0 = *(const float4*)(arow + (size_t)(s + 2) * KS_ + 0);
            an1 = *(const float4*)(arow + (size_t)(s + 2) * KS_ + 4);
            an2 = *(const float4*)(arow + (size_t)(s + 2) * KS_ + 32);
            an3 = *(const float4*)(arow + (size_t)(s + 2) * KS_ + 36);
        }
        __syncthreads();
        if (s + 1 < NST_) {
            *(uint4*)&bs[buf ^ 1][srow][((g2    ) ^ swz) * 8] = bv0;
            *(uint4*)&bs[buf ^ 1][srow][((g2 + 1) ^ swz) * 8] = bv1;
            if (s + 2 < NST_) {
                bv0 = *(const uint4*)(ysrc + (size_t)(s + 2) * KS_);
                bv1 = *(const uint4*)(ysrc + (size_t)(s + 2) * KS_ + 8);
            }
            __syncthreads();
        }
    }

    // wk-reduction + epilogue. C/D layout: col=c*16+l15, row_loc=kg*4+j (m89).
    if (wk == 1) {
#pragma unroll
        for (int c = 0; c < 4; ++c) {
            f32x4 acc = (c == 0) ? acc0 : (c == 1) ? acc1 : (c == 2) ? acc2 : acc3;
#pragma unroll
            for (int j = 0; j < 4; ++j)
                red[wm][kg * 4 + j][c * 16 + l15] = acc[j];
        }
    }
    __syncthreads();
    if (wk == 0) {
        const float alpha0 = *alpha0p;
        const size_t diff_off = (size_t)R_ * N_ * D_;   // out = [latent | diffusions]
#pragma unroll
        for (int c = 0; c < 4; ++c) {
            f32x4 acc = (c == 0) ? acc0 : (c == 1) ? acc1 : (c == 2) ? acc2 : acc3;
            int col = c * 16 + l15;
            float b = fc_b[r * D_ + col];
#pragma unroll
            for (int j = 0; j < 4; ++j) {
                int rloc = kg * 4 + j;
                float v = acc[j] + red[wm][rloc][col] + b;
                v = (v >= 0.f) ? v : alpha0 * v;
                out[diff_off + ((size_t)(r * N_ + rb * 64 + wm * 16 + rloc)) * D_ + col] = v;
            }
        }
    }
}

// Kernel 3: 1x1 conv over relation channels + PReLU.
__global__ __launch_bounds__(256) void conv_kernel(
    const float* __restrict__ conv_w, const float* __restrict__ conv_b,
    const float* __restrict__ alpha1p, float* __restrict__ out) {
    const size_t nd = (size_t)N_ * D_;
    const size_t diff_off = (size_t)R_ * nd;
    size_t i = ((size_t)blockIdx.x * 256 + threadIdx.x) * 4;

    float4 d0 = *(const float4*)(out + diff_off + 0 * nd + i);
    float4 d1 = *(const float4*)(out + diff_off + 1 * nd + i);
    float4 d2 = *(const float4*)(out + diff_off + 2 * nd + i);
    float4 d3 = *(const float4*)(out + diff_off + 3 * nd + i);
    const float alpha1 = *alpha1p;
#pragma unroll
    for (int s = 0; s < R_; ++s) {
        float w0 = conv_w[s * R_ + 0], w1 = conv_w[s * R_ + 1];
        float w2 = conv_w[s * R_ + 2], w3 = conv_w[s * R_ + 3];
        float cb = conv_b[s];
        float4 v;
        v.x = cb + w0 * d0.x + w1 * d1.x + w2 * d2.x + w3 * d3.x;
        v.y = cb + w0 * d0.y + w1 * d1.y + w2 * d2.y + w3 * d3.y;
        v.z = cb + w0 * d0.z + w1 * d1.z + w2 * d2.z + w3 * d3.z;
        v.w = cb + w0 * d0.w + w1 * d1.w + w2 * d2.w + w3 * d3.w;
        v.x = (v.x >= 0.f) ? v.x : alpha1 * v.x;
        v.y = (v.y >= 0.f) ? v.y : alpha1 * v.y;
        v.z = (v.z >= 0.f) ? v.z : alpha1 * v.z;
        v.w = (v.w >= 0.f) ? v.w : alpha1 * v.w;
        *(float4*)(out + s * nd + i) = v;
    }
}

extern "C" void kernel_launch(void* const* d_in, const int* in_sizes, int n_in,
                              void* d_out, int out_size, void* d_ws, size_t ws_size,
                              hipStream_t stream) {
    const float* theta  = (const float*)d_in[0];
    const float* tt     = (const float*)d_in[1];
    const float* a      = (const float*)d_in[2];
    const float* x      = (const float*)d_in[3];
    const float* fc_w   = (const float*)d_in[4];
    const float* fc_b   = (const float*)d_in[5];
    const float* conv_w = (const float*)d_in[6];
    const float* conv_b = (const float*)d_in[7];
    const float* alpha0 = (const float*)d_in[8];
    const float* alpha1 = (const float*)d_in[9];
    float* out = (float*)d_out;
    unsigned short* ycombT = (unsigned short*)d_ws;   // 2 MiB bf16

    prep_kernel<<<dim3(R_ * (N_ / 64)), dim3(256), 0, stream>>>(theta, tt, x, fc_w, ycombT);
    gemm_kernel<<<dim3((N_ / 64) * R_), dim3(512), 0, stream>>>(a, ycombT, fc_b, alpha0, out);
    conv_kernel<<<dim3((N_ * D_) / 4 / 256), dim3(256), 0, stream>>>(conv_w, conv_b, alpha1, out);
}